// Round 1
// baseline (166.069 us; speedup 1.0000x reference)
//
#include <hip/hip_runtime.h>

#define NPTS 4096
#define N0V  10242
#define C0C  128
#define INCH 19
#define MROWS 8192
#define EPSV 1e-5f

__device__ __forceinline__ float fmul(float a, float b){ return __fmul_rn(a,b); }
__device__ __forceinline__ float fadd(float a, float b){ return __fadd_rn(a,b); }
__device__ __forceinline__ float fsub(float a, float b){ return __fsub_rn(a,b); }

// ---------------- K1: first-hit search + gather + concat into x0 [8192][160] ----------------
__global__ __launch_bounds__(256) void k_feat(
    const float* __restrict__ orig, const float* __restrict__ proj,
    const float* __restrict__ vertex, const int* __restrict__ nidx,
    float* __restrict__ x0)
{
  const int lane = threadIdx.x & 63;
  const int w    = threadIdx.x >> 6;
  const int p    = blockIdx.x * 4 + w;       // 0..8191
  const int b    = p >> 12;
  const int n    = p & 4095;

  // scalar params (wave-uniform, mirror reference op order exactly)
  float v0x = vertex[0], v0y = vertex[1], v0z = vertex[2];
  float rr0 = fadd(fadd(fmul(v0x,v0x), fmul(v0y,v0y)), fmul(v0z,v0z));
  float r   = __fsqrt_rn(rr0);
  float rr  = fmul(r, r);                     // reference uses r*r, not sum directly
  int   j0  = nidx[0];
  float ax = vertex[3*j0], ay = vertex[3*j0+1], az = vertex[3*j0+2];
  float dx = fsub(v0x,ax), dy = fsub(v0y,ay), dz = fsub(v0z,az);
  float t2 = fadd(fadd(fmul(dx,dx), fmul(dy,dy)), fmul(dz,dz));

  const float* ob = orig + (b*INCH)*NPTS + n;
  float x = ob[0], y = ob[NPTS], z = ob[2*NPTS];
  float nrm = __fsqrt_rn(fadd(fadd(fmul(x,x), fmul(y,y)), fmul(z,z)));
  float s  = __fdiv_rn(r, nrm);
  float px = fmul(x,s), py = fmul(y,s), pz = fmul(z,s);

  // chunked early-exit scan for first m with d2 <= t2
  int first = 0; bool has = false;
  for (int c0 = 0; c0 < N0V; c0 += 64) {
    int m = c0 + lane;
    bool hit = false;
    if (m < N0V) {
      float vx = vertex[3*m], vy = vertex[3*m+1], vz = vertex[3*m+2];
      float v2 = fadd(fadd(fmul(vx,vx), fmul(vy,vy)), fmul(vz,vz));
      float dt = fadd(fadd(fmul(px,vx), fmul(py,vy)), fmul(pz,vz));
      float d2 = fsub(fadd(rr, v2), fmul(2.0f, dt));
      hit = (d2 <= t2);
    }
    unsigned long long bal = __ballot(hit);
    if (bal) { first = c0 + __builtin_ctzll(bal); has = true; break; }
  }

  // write row: [0..18] original channels, [19..146] gathered feature, [147..159] zero pad
  float* row = x0 + (long)p * 160;
  const float* pb = proj + (long)b * C0C * N0V;
  for (int idx = lane; idx < 160; idx += 64) {
    float v;
    if (idx < INCH)            v = orig[(b*INCH + idx)*NPTS + n];
    else if (idx < INCH + C0C) v = has ? pb[(idx-INCH)*N0V + first] : 0.0f;
    else                       v = 0.0f;
    row[idx] = v;
  }
}

// ---------------- K0: pack W^T as [K/4][128][4] (zero-padded to K=160 for layer 0) ----------------
__global__ __launch_bounds__(256) void k_prep_w(
    const float* __restrict__ W0, const float* __restrict__ W1, const float* __restrict__ W2,
    float* __restrict__ wt0, float* __restrict__ wt1, float* __restrict__ wt2)
{
  int t = blockIdx.x * 256 + threadIdx.x;
  if (t < 40*128) {
    int c4 = t >> 7, o = t & 127;
    float4 v; float* vv = (float*)&v;
    #pragma unroll
    for (int j = 0; j < 4; j++) { int c = c4*4 + j; vv[j] = (c < 147) ? W0[o*147 + c] : 0.0f; }
    ((float4*)wt0)[t] = v;
  } else if (t < 72*128) {
    int u = t - 40*128; int c4 = u >> 7, o = u & 127;
    float4 v; float* vv = (float*)&v;
    #pragma unroll
    for (int j = 0; j < 4; j++) vv[j] = W1[o*128 + c4*4 + j];
    ((float4*)wt1)[u] = v;
  } else if (t < 104*128) {
    int u = t - 72*128; int c4 = u >> 7, o = u & 127;
    float4 v; float* vv = (float*)&v;
    #pragma unroll
    for (int j = 0; j < 4; j++) vv[j] = W2[o*128 + c4*4 + j];
    ((float4*)wt2)[u] = v;
  }
}

// ---------------- GEMM: y[32 rows][128] = x @ W^T + b, with optional fused affine+relu on input,
//                  plus per-block partial sums for BN stats ----------------
template<int K4, bool AFF>
__global__ __launch_bounds__(256) void k_mm(
    const float* __restrict__ X, const float* __restrict__ wtp,
    const float* __restrict__ bias, const float* __restrict__ stIn,
    float* __restrict__ Y, float* __restrict__ part)
{
  constexpr int KK = K4*4;
  __shared__ float xs[32*KK];
  __shared__ float red[2][128][2];
  const int t = threadIdx.x;
  const int blk = blockIdx.x;

  // stage 32 rows of X into LDS (apply prev-layer BN affine + relu if AFF)
  const float4* s4 = (const float4*)(X + (long)blk * 32 * KK);
  float4* d4 = (float4*)xs;
  for (int i = t; i < 32*K4; i += 256) {
    float4 v = s4[i];
    if constexpr (AFF) {
      int c = (i*4) & 127;
      v.x = fmaxf(fmaf(v.x, stIn[c  ], stIn[128+c  ]), 0.0f);
      v.y = fmaxf(fmaf(v.y, stIn[c+1], stIn[128+c+1]), 0.0f);
      v.z = fmaxf(fmaf(v.z, stIn[c+2], stIn[128+c+2]), 0.0f);
      v.w = fmaxf(fmaf(v.w, stIn[c+3], stIn[128+c+3]), 0.0f);
    }
    d4[i] = v;
  }
  __syncthreads();

  const int o = t & 127, h = t >> 7;
  float acc[16];
  #pragma unroll
  for (int r = 0; r < 16; r++) acc[r] = 0.0f;

  const float4* wp = ((const float4*)wtp) + o;           // [c4][o] packed float4
  const float4* xbase = (const float4*)(xs + h*16*KK);   // this half-wave's 16 rows
  for (int c4 = 0; c4 < K4; c4++) {
    float4 wv = wp[c4*128];
    #pragma unroll
    for (int r = 0; r < 16; r++) {
      float4 xv = xbase[r*K4 + c4];                      // LDS broadcast (wave-uniform addr)
      acc[r] = fmaf(xv.x, wv.x, acc[r]);
      acc[r] = fmaf(xv.y, wv.y, acc[r]);
      acc[r] = fmaf(xv.z, wv.z, acc[r]);
      acc[r] = fmaf(xv.w, wv.w, acc[r]);
    }
  }

  float bo = bias[o];
  float s1 = 0.0f, s2 = 0.0f;
  const int row0 = blk*32 + h*16;
  #pragma unroll
  for (int r = 0; r < 16; r++) {
    float yv = acc[r] + bo;
    Y[(long)(row0 + r)*128 + o] = yv;                    // coalesced across wave (consecutive o)
    s1 += yv;
    s2 = fmaf(yv, yv, s2);
  }
  red[h][o][0] = s1; red[h][o][1] = s2;
  __syncthreads();
  if (t < 128) {
    part[blk*128 + t]           = red[0][t][0] + red[1][t][0];
    part[256*128 + blk*128 + t] = red[0][t][1] + red[1][t][1];
  }
}

// ---------------- stats reduce: 256 block-partials -> per-channel scale/shift ----------------
__global__ __launch_bounds__(256) void k_stats(
    const float* __restrict__ part, const float* __restrict__ g,
    const float* __restrict__ be, float* __restrict__ stOut)
{
  __shared__ float red[2][128][2];
  const int t = threadIdx.x;
  const int o = t & 127, h = t >> 7;
  float s = 0.0f, q = 0.0f;
  for (int blk = h*128; blk < h*128 + 128; blk++) {
    s += part[blk*128 + o];
    q += part[32768 + blk*128 + o];
  }
  red[h][o][0] = s; red[h][o][1] = q;
  __syncthreads();
  if (t < 128) {
    float S = red[0][t][0] + red[1][t][0];
    float Q = red[0][t][1] + red[1][t][1];
    float mean = S * (1.0f/8192.0f);
    float var  = Q * (1.0f/8192.0f) - mean*mean;
    float inv  = 1.0f / __fsqrt_rn(var + EPSV);
    float sc   = g[t] * inv;
    stOut[t]       = sc;
    stOut[128 + t] = be[t] - mean * sc;
  }
}

// ---------------- final: affine+relu + transpose to (B,128,N) ----------------
__global__ __launch_bounds__(256) void k_final(
    const float* __restrict__ Y, const float* __restrict__ st, float* __restrict__ out)
{
  __shared__ float tile[64*129];
  const int t = threadIdx.x;
  const int row0 = blockIdx.x * 64;                      // 128 blocks, 64 rows each (within one b)
  const float4* s4 = (const float4*)(Y + (long)row0*128);
  for (int i = t; i < 64*32; i += 256) {
    float4 v = s4[i];
    int r = i >> 5, c = (i & 31) * 4;
    v.x = fmaxf(fmaf(v.x, st[c  ], st[128+c  ]), 0.0f);
    v.y = fmaxf(fmaf(v.y, st[c+1], st[128+c+1]), 0.0f);
    v.z = fmaxf(fmaf(v.z, st[c+2], st[128+c+2]), 0.0f);
    v.w = fmaxf(fmaf(v.w, st[c+3], st[128+c+3]), 0.0f);
    float* drow = tile + r*129 + c;
    drow[0]=v.x; drow[1]=v.y; drow[2]=v.z; drow[3]=v.w;
  }
  __syncthreads();
  const int b = row0 >> 12, n0 = row0 & 4095;
  const int l = t & 63, q = t >> 6;
  float* ob = out + (long)b*128*4096 + n0;
  for (int oo = q*32; oo < q*32 + 32; oo++) {
    ob[(long)oo*4096 + l] = tile[l*129 + oo];            // 64 lanes -> 256B contiguous store
  }
}

extern "C" void kernel_launch(void* const* d_in, const int* in_sizes, int n_in,
                              void* d_out, int out_size, void* d_ws, size_t ws_size,
                              hipStream_t stream)
{
  const float* orig   = (const float*)d_in[0];
  const float* proj   = (const float*)d_in[1];
  const float* vertex = (const float*)d_in[2];
  const int*   nidx   = (const int*)d_in[3];
  const float* W0 = (const float*)d_in[4];
  const float* b0 = (const float*)d_in[5];
  const float* g0 = (const float*)d_in[6];
  const float* be0= (const float*)d_in[7];
  const float* W1 = (const float*)d_in[8];
  const float* b1 = (const float*)d_in[9];
  const float* g1 = (const float*)d_in[10];
  const float* be1= (const float*)d_in[11];
  const float* W2 = (const float*)d_in[12];
  const float* b2 = (const float*)d_in[13];
  const float* g2 = (const float*)d_in[14];
  const float* be2= (const float*)d_in[15];
  float* out = (float*)d_out;

  float* ws  = (float*)d_ws;
  float* wt0 = ws;                 // 40*128*4 = 20480 floats
  float* wt1 = wt0 + 20480;        // 16384
  float* wt2 = wt1 + 16384;        // 16384
  float* st0 = wt2 + 16384;        // 256 (scale|shift)
  float* st1 = st0 + 256;
  float* st2 = st1 + 256;
  float* part= st2 + 256;          // 2*256*128 = 65536
  float* x0  = part + 65536;       // 8192*160
  float* y0  = x0 + 8192*160;      // 8192*128
  float* y1  = y0 + 8192*128;
  float* y2  = y1 + 8192*128;

  k_prep_w<<<52, 256, 0, stream>>>(W0, W1, W2, wt0, wt1, wt2);
  k_feat<<<2048, 256, 0, stream>>>(orig, proj, vertex, nidx, x0);
  k_mm<40,false><<<256, 256, 0, stream>>>(x0, wt0, b0, nullptr, y0, part);
  k_stats<<<1, 256, 0, stream>>>(part, g0, be0, st0);
  k_mm<32,true><<<256, 256, 0, stream>>>(y0, wt1, b1, st0, y1, part);
  k_stats<<<1, 256, 0, stream>>>(part, g1, be1, st1);
  k_mm<32,true><<<256, 256, 0, stream>>>(y1, wt2, b2, st1, y2, part);
  k_stats<<<1, 256, 0, stream>>>(part, g2, be2, st2);
  k_final<<<128, 256, 0, stream>>>(y2, st2, out);
}

// Round 2
// 143.670 us; speedup vs baseline: 1.1559x; 1.1559x over previous
//
#include <hip/hip_runtime.h>
#include <hip/hip_cooperative_groups.h>

namespace cg = cooperative_groups;

#define NPTS 4096
#define N0V  10242
#define EPSV 1e-5f

__device__ __forceinline__ float fmul(float a,float b){return __fmul_rn(a,b);}
__device__ __forceinline__ float fadd(float a,float b){return __fadd_rn(a,b);}
__device__ __forceinline__ float fsub(float a,float b){return __fsub_rn(a,b);}

// ---------------- pack W^T as [K/4][128][float4] (zero-pad to K=160 for layer 0) ----------------
__global__ __launch_bounds__(256) void k_prep_w(
    const float* __restrict__ W0, const float* __restrict__ W1, const float* __restrict__ W2,
    float* __restrict__ wt0, float* __restrict__ wt1, float* __restrict__ wt2)
{
  int t = blockIdx.x * 256 + threadIdx.x;
  if (t < 40*128) {
    int c4 = t >> 7, o = t & 127;
    float4 v; float* vv = (float*)&v;
    #pragma unroll
    for (int j = 0; j < 4; j++) { int c = c4*4 + j; vv[j] = (c < 147) ? W0[o*147 + c] : 0.0f; }
    ((float4*)wt0)[t] = v;
  } else if (t < 72*128) {
    int u = t - 40*128; int c4 = u >> 7, o = u & 127;
    float4 v; float* vv = (float*)&v;
    #pragma unroll
    for (int j = 0; j < 4; j++) vv[j] = W1[o*128 + c4*4 + j];
    ((float4*)wt1)[u] = v;
  } else if (t < 104*128) {
    int u = t - 72*128; int c4 = u >> 7, o = u & 127;
    float4 v; float* vv = (float*)&v;
    #pragma unroll
    for (int j = 0; j < 4; j++) vv[j] = W2[o*128 + c4*4 + j];
    ((float4*)wt2)[u] = v;
  }
}

struct Params {
  const float* orig; const float* proj; const float* vertex; const int* nidx;
  const float* wt0; const float* wt1; const float* wt2;
  const float* b0; const float* g0; const float* be0;
  const float* b1; const float* g1; const float* be1;
  const float* b2; const float* g2; const float* be2;
  float* part0; float* part1; float* part2; float* out;
};

// dot-product core: thread = (o, rgrp); 8 rows each; x from LDS (broadcast reads), W from L2
template<int K4>
__device__ __forceinline__ void mm_compute(const float4* xs4, int xstr4,
                                           const float* __restrict__ wt,
                                           const float* __restrict__ bias,
                                           int o, int rgrp, float* acc)
{
  #pragma unroll
  for (int r=0;r<8;r++) acc[r]=0.0f;
  const float4* wp = ((const float4*)wt) + o;
  for (int c4=0;c4<K4;c4++){
    float4 wv = wp[c4*128];
    #pragma unroll
    for (int r=0;r<8;r++){
      float4 xv = xs4[(rgrp*8+r)*xstr4 + c4];
      acc[r]=fmaf(xv.x,wv.x,acc[r]);
      acc[r]=fmaf(xv.y,wv.y,acc[r]);
      acc[r]=fmaf(xv.z,wv.z,acc[r]);
      acc[r]=fmaf(xv.w,wv.w,acc[r]);
    }
  }
  float bo = bias[o];
  #pragma unroll
  for (int r=0;r<8;r++) acc[r] += bo;
}

// per-block partial sum/sumsq of y -> part[blk]
__device__ __forceinline__ void block_part(const float* acc, float* redp, float* part,
                                           int blk, int o, int rgrp, int t)
{
  float s1=0.0f, s2=0.0f;
  #pragma unroll
  for (int r=0;r<8;r++){ s1 += acc[r]; s2 = fmaf(acc[r],acc[r],s2); }
  redp[(rgrp*128+o)*2]   = s1;
  redp[(rgrp*128+o)*2+1] = s2;
  __syncthreads();
  if (t < 128) {
    float S = redp[t*2] + redp[(128+t)*2] + redp[(256+t)*2] + redp[(384+t)*2];
    float Q = redp[t*2+1] + redp[(128+t)*2+1] + redp[(256+t)*2+1] + redp[(384+t)*2+1];
    part[blk*128+t]         = S;
    part[32768 + blk*128+t] = Q;
  }
}

// redundant per-block reduction of all 256 partials -> scale/shift in LDS
__device__ __forceinline__ void stats_phase(const float* __restrict__ part,
                                            const float* __restrict__ g,
                                            const float* __restrict__ be,
                                            float* red2, float* stS, float* stB, int t)
{
  int q    = t >> 8;         // 0=sum, 1=sumsq
  int half = (t >> 7) & 1;   // which 128 blocks
  int ch   = t & 127;
  const float* base = part + q*32768 + (half*128)*128 + ch;
  float a0=0,a1=0,a2=0,a3=0;
  #pragma unroll 8
  for (int bi=0; bi<128; bi+=4){
    a0 += base[(bi+0)*128];
    a1 += base[(bi+1)*128];
    a2 += base[(bi+2)*128];
    a3 += base[(bi+3)*128];
  }
  red2[(q*2+half)*128 + ch] = (a0+a1)+(a2+a3);
  __syncthreads();
  if (t < 128) {
    float S = red2[t] + red2[128+t];
    float Q = red2[256+t] + red2[384+t];
    float mean = S * (1.0f/8192.0f);
    float var  = Q * (1.0f/8192.0f) - mean*mean;
    float inv  = 1.0f / __fsqrt_rn(var + EPSV);
    float sc = g[t]*inv;
    stS[t] = sc;
    stB[t] = be[t] - mean*sc;
  }
  __syncthreads();
}

// in-place affine+relu on a [32][132] LDS tile (f4 stride 33)
__device__ __forceinline__ void transform_buf(float* buf, const float* stS, const float* stB, int t)
{
  float4* b4 = (float4*)buf;
  #pragma unroll
  for (int ii=0; ii<2; ii++){
    int i = t + ii*512;
    int r = i >> 5, c4 = i & 31;
    float4 v = b4[r*33+c4];
    int c = c4*4;
    v.x = fmaxf(fmaf(v.x, stS[c  ], stB[c  ]), 0.0f);
    v.y = fmaxf(fmaf(v.y, stS[c+1], stB[c+1]), 0.0f);
    v.z = fmaxf(fmaf(v.z, stS[c+2], stB[c+2]), 0.0f);
    v.w = fmaxf(fmaf(v.w, stS[c+3], stB[c+3]), 0.0f);
    b4[r*33+c4] = v;
  }
  __syncthreads();
}

__global__ __launch_bounds__(512) void k_fused(Params p)
{
  __shared__ __align__(16) float bufA[32*160];   // x0 [32][160]; later y1/x2 as [32][132]
  __shared__ __align__(16) float bufB[32*132];   // y0/x1; later y2/x3 as [32][132]
  __shared__ float redp[1024];
  __shared__ float red2[512];
  __shared__ float stS[128];
  __shared__ float stB[128];

  cg::grid_group grid = cg::this_grid();

  const int t    = threadIdx.x;
  const int blk  = blockIdx.x;
  const int lane = t & 63;
  const int w    = t >> 6;          // wave 0..7
  const int b    = blk >> 7;
  const int n0   = (blk & 127) * 32;
  const int o    = t & 127;
  const int rgrp = t >> 7;          // 0..3 -> rows rgrp*8..+7

  // ---------------- feat: block's 32 rows -> bufA[row][0..159] ----------------
  {
    float v0x=p.vertex[0], v0y=p.vertex[1], v0z=p.vertex[2];
    float r  = __fsqrt_rn(fadd(fadd(fmul(v0x,v0x),fmul(v0y,v0y)),fmul(v0z,v0z)));
    float rr = fmul(r,r);
    int j0 = p.nidx[0];
    float ax=p.vertex[3*j0], ay=p.vertex[3*j0+1], az=p.vertex[3*j0+2];
    float dx=fsub(v0x,ax), dy=fsub(v0y,ay), dz=fsub(v0z,az);
    float t2 = fadd(fadd(fmul(dx,dx),fmul(dy,dy)),fmul(dz,dz));

    int firsts[4]; int hass[4];
    #pragma unroll
    for (int rr_i=0; rr_i<4; rr_i++){
      const int row = w*4 + rr_i;
      const int n = n0 + row;
      const float* ob = p.orig + (b*19)*NPTS + n;
      float x=ob[0], y=ob[NPTS], z=ob[2*NPTS];
      float nrm = __fsqrt_rn(fadd(fadd(fmul(x,x),fmul(y,y)),fmul(z,z)));
      float s = __fdiv_rn(r,nrm);
      float px=fmul(x,s), py=fmul(y,s), pz=fmul(z,s);
      int first=0, has=0;
      for (int c0=0; c0<N0V; c0+=64){
        int m=c0+lane; bool hit=false;
        if (m<N0V){
          float vx=p.vertex[3*m], vy=p.vertex[3*m+1], vz=p.vertex[3*m+2];
          float v2=fadd(fadd(fmul(vx,vx),fmul(vy,vy)),fmul(vz,vz));
          float dt=fadd(fadd(fmul(px,vx),fmul(py,vy)),fmul(pz,vz));
          float d2=fsub(fadd(rr,v2),fmul(2.0f,dt));
          hit = (d2<=t2);
        }
        unsigned long long bal=__ballot(hit);
        if (bal){ first=c0+__builtin_ctzll(bal); has=1; break; }
      }
      firsts[rr_i]=first; hass[rr_i]=has;
    }
    const float* pb = p.proj + (long)b*128*N0V;
    #pragma unroll
    for (int rr_i=0; rr_i<4; rr_i++){
      const int row = w*4 + rr_i;
      const int n = n0 + row;
      #pragma unroll
      for (int k=0;k<3;k++){
        int idx = lane + k*64;
        if (idx < 160){
          float v;
          if (idx < 19)        v = p.orig[(b*19+idx)*NPTS + n];
          else if (idx < 147)  v = hass[rr_i] ? pb[(long)(idx-19)*N0V + firsts[rr_i]] : 0.0f;
          else                 v = 0.0f;
          bufA[row*160 + idx] = v;
        }
      }
    }
  }
  __syncthreads();

  float acc[8];

  // ---------------- layer 0 ----------------
  mm_compute<40>((const float4*)bufA, 40, p.wt0, p.b0, o, rgrp, acc);
  #pragma unroll
  for (int r=0;r<8;r++) bufB[(rgrp*8+r)*132 + o] = acc[r];
  block_part(acc, redp, p.part0, blk, o, rgrp, t);
  grid.sync();
  stats_phase(p.part0, p.g0, p.be0, red2, stS, stB, t);
  transform_buf(bufB, stS, stB, t);

  // ---------------- layer 1 ----------------
  mm_compute<32>((const float4*)bufB, 33, p.wt1, p.b1, o, rgrp, acc);
  #pragma unroll
  for (int r=0;r<8;r++) bufA[(rgrp*8+r)*132 + o] = acc[r];
  block_part(acc, redp, p.part1, blk, o, rgrp, t);
  grid.sync();
  stats_phase(p.part1, p.g1, p.be1, red2, stS, stB, t);
  transform_buf(bufA, stS, stB, t);

  // ---------------- layer 2 ----------------
  mm_compute<32>((const float4*)bufA, 33, p.wt2, p.b2, o, rgrp, acc);
  block_part(acc, redp, p.part2, blk, o, rgrp, t);
  grid.sync();
  stats_phase(p.part2, p.g2, p.be2, red2, stS, stB, t);

  // apply affine+relu in regs, bounce through LDS for coalesced transposed store
  {
    float ss = stS[o], sb = stB[o];
    #pragma unroll
    for (int r=0;r<8;r++){
      float v = fmaxf(fmaf(acc[r], ss, sb), 0.0f);
      bufB[(rgrp*8+r)*132 + o] = v;
    }
  }
  __syncthreads();
  {
    float* ob = p.out + (long)b*128*NPTS + n0;
    #pragma unroll
    for (int ii=0; ii<8; ii++){
      int i = t + ii*512;
      int oo = i >> 5, j = i & 31;
      ob[(long)oo*NPTS + j] = bufB[j*132 + oo];
    }
  }
}

extern "C" void kernel_launch(void* const* d_in, const int* in_sizes, int n_in,
                              void* d_out, int out_size, void* d_ws, size_t ws_size,
                              hipStream_t stream)
{
  const float* orig   = (const float*)d_in[0];
  const float* proj   = (const float*)d_in[1];
  const float* vertex = (const float*)d_in[2];
  const int*   nidx   = (const int*)d_in[3];
  const float* W0 = (const float*)d_in[4];
  const float* b0 = (const float*)d_in[5];
  const float* g0 = (const float*)d_in[6];
  const float* be0= (const float*)d_in[7];
  const float* W1 = (const float*)d_in[8];
  const float* b1 = (const float*)d_in[9];
  const float* g1 = (const float*)d_in[10];
  const float* be1= (const float*)d_in[11];
  const float* W2 = (const float*)d_in[12];
  const float* b2 = (const float*)d_in[13];
  const float* g2 = (const float*)d_in[14];
  const float* be2= (const float*)d_in[15];
  float* out = (float*)d_out;

  float* ws    = (float*)d_ws;
  float* part0 = ws;                    // 2*256*128 = 65536 floats
  float* part1 = ws + 65536;
  float* part2 = ws + 131072;
  float* wt0   = ws + 196608;           // 40*128*4 = 20480
  float* wt1   = wt0 + 20480;           // 16384
  float* wt2   = wt1 + 16384;           // 16384

  k_prep_w<<<52, 256, 0, stream>>>(W0, W1, W2, wt0, wt1, wt2);

  Params p{orig, proj, vertex, nidx, wt0, wt1, wt2,
           b0, g0, be0, b1, g1, be1, b2, g2, be2,
           part0, part1, part2, out};
  void* args[] = {(void*)&p};
  hipLaunchCooperativeKernel((const void*)k_fused, dim3(256), dim3(512), args, 0, stream);
}

// Round 4
// 95.748 us; speedup vs baseline: 1.7344x; 1.5005x over previous
//
#include <hip/hip_runtime.h>

#define NPTS 4096
#define N0V  10242
#define EPSV 1e-5f
#define NBLK 256
#define SLOTS 16

__device__ __forceinline__ float fmul(float a,float b){return __fmul_rn(a,b);}
__device__ __forceinline__ float fadd(float a,float b){return __fadd_rn(a,b);}
__device__ __forceinline__ float fsub(float a,float b){return __fsub_rn(a,b);}

// ---------------- prep: pack W^T as [K/4][128][float4] + zero acc slots/counters ----------------
__global__ __launch_bounds__(256) void k_init(
    const float* __restrict__ W0, const float* __restrict__ W1, const float* __restrict__ W2,
    float* __restrict__ wt0, float* __restrict__ wt1, float* __restrict__ wt2,
    float* __restrict__ accg, int* __restrict__ cnt)
{
  int t = blockIdx.x * 256 + threadIdx.x;
  if (t < 40*128) {
    int c4 = t >> 7, o = t & 127;
    float4 v; float* vv = (float*)&v;
    #pragma unroll
    for (int j = 0; j < 4; j++) { int c = c4*4 + j; vv[j] = (c < 147) ? W0[o*147 + c] : 0.0f; }
    ((float4*)wt0)[t] = v;
  } else if (t < 72*128) {
    int u = t - 40*128; int c4 = u >> 7, o = u & 127;
    float4 v; float* vv = (float*)&v;
    #pragma unroll
    for (int j = 0; j < 4; j++) vv[j] = W1[o*128 + c4*4 + j];
    ((float4*)wt1)[u] = v;
  } else if (t < 104*128) {
    int u = t - 72*128; int c4 = u >> 7, o = u & 127;
    float4 v; float* vv = (float*)&v;
    #pragma unroll
    for (int j = 0; j < 4; j++) vv[j] = W2[o*128 + c4*4 + j];
    ((float4*)wt2)[u] = v;
  } else {
    int u = t - 104*128;             // [0, 3072) across the 64-block grid
    float4 z = make_float4(0.f,0.f,0.f,0.f);
    ((float4*)accg)[u] = z;          // zero 3*16*256 = 12288 floats
    if (u < 4) cnt[u] = 0;
  }
}

struct Params {
  const float* orig; const float* proj; const float* vertex; const int* nidx;
  const float* wt0; const float* wt1; const float* wt2;
  const float* b0; const float* g0; const float* be0;
  const float* b1; const float* g1; const float* be1;
  const float* b2; const float* g2; const float* be2;
  float* accg; int* cnt; float* out;
};

// dot-product core: thread = (o, rgrp); 8 rows each; x from LDS (broadcast), W from L2
template<int K4>
__device__ __forceinline__ void mm_compute(const float4* xs4, int xstr4,
                                           const float* __restrict__ wt,
                                           const float* __restrict__ bias,
                                           int o, int rgrp, float* acc)
{
  #pragma unroll
  for (int r=0;r<8;r++) acc[r]=0.0f;
  const float4* wp = ((const float4*)wt) + o;
  #pragma unroll 4
  for (int c4=0;c4<K4;c4++){
    float4 wv = wp[c4*128];
    #pragma unroll
    for (int r=0;r<8;r++){
      float4 xv = xs4[(rgrp*8+r)*xstr4 + c4];
      acc[r]=fmaf(xv.x,wv.x,acc[r]);
      acc[r]=fmaf(xv.y,wv.y,acc[r]);
      acc[r]=fmaf(xv.z,wv.z,acc[r]);
      acc[r]=fmaf(xv.w,wv.w,acc[r]);
    }
  }
  float bo = bias[o];
  #pragma unroll
  for (int r=0;r<8;r++) acc[r] += bo;
}

// partials -> global atomic slots -> counter barrier -> redundant small stats -> stS/stB in LDS
__device__ __forceinline__ void layer_stats(const float* acc8,
    float* __restrict__ accL, int* __restrict__ cntp,
    const float* __restrict__ g, const float* __restrict__ be,
    float* redp, float* red2, float* stS, float* stB, int t, int blk)
{
  float s1=0.0f, s2=0.0f;
  #pragma unroll
  for (int r=0;r<8;r++){ s1 += acc8[r]; s2 = fmaf(acc8[r],acc8[r],s2); }
  int o = t & 127, rgrp = t >> 7;
  redp[rgrp*128 + o]       = s1;
  redp[512 + rgrp*128 + o] = s2;
  __syncthreads();
  if (t < 256){
    int q = t >> 7, ch = t & 127;
    const float* rp = redp + q*512 + ch;
    float v = (rp[0] + rp[128]) + (rp[256] + rp[384]);
    atomicAdd(&accL[(blk & (SLOTS-1))*256 + t], v);   // device-scope, coherent point
  }
  __syncthreads();   // s_waitcnt vmcnt(0): this block's atomics globally performed
  if (t == 0){
    __hip_atomic_fetch_add(cntp, 1, __ATOMIC_RELEASE, __HIP_MEMORY_SCOPE_AGENT);
    while (__hip_atomic_load(cntp, __ATOMIC_ACQUIRE, __HIP_MEMORY_SCOPE_AGENT) < NBLK)
      __builtin_amdgcn_s_sleep(2);
  }
  __syncthreads();
  if (t < 256){
    float v = 0.0f;
    #pragma unroll
    for (int s=0;s<SLOTS;s++)
      v += __hip_atomic_load(&accL[s*256 + t], __ATOMIC_RELAXED, __HIP_MEMORY_SCOPE_AGENT);
    red2[t] = v;
  }
  __syncthreads();
  if (t < 128){
    float S = red2[t], Q = red2[128 + t];
    float mean = S * (1.0f/8192.0f);
    float var  = Q * (1.0f/8192.0f) - mean*mean;
    float inv  = 1.0f / __fsqrt_rn(var + EPSV);
    float sc = g[t]*inv;
    stS[t] = sc;
    stB[t] = be[t] - mean*sc;
  }
  __syncthreads();
}

// in-place affine+relu on [32][132] tile (f4 stride 33, cols 0..127)
__device__ __forceinline__ void transform_buf(float* buf, const float* stS, const float* stB, int t)
{
  float4* b4 = (float4*)buf;
  #pragma unroll
  for (int ii=0; ii<2; ii++){
    int i = t + ii*512;
    int r = i >> 5, c4 = i & 31;
    float4 v = b4[r*33 + c4];
    int c = c4*4;
    v.x = fmaxf(fmaf(v.x, stS[c  ], stB[c  ]), 0.0f);
    v.y = fmaxf(fmaf(v.y, stS[c+1], stB[c+1]), 0.0f);
    v.z = fmaxf(fmaf(v.z, stS[c+2], stB[c+2]), 0.0f);
    v.w = fmaxf(fmaf(v.w, stS[c+3], stB[c+3]), 0.0f);
    b4[r*33 + c4] = v;
  }
  __syncthreads();
}

__global__ __launch_bounds__(512) void k_fused(Params p)
{
  __shared__ __align__(16) float bufA[32*160];   // x0 [32][160]; later y1/x2 [32][132]
  __shared__ __align__(16) float bufB[32*132];   // y0/x1; later y2
  __shared__ float redp[1024];
  __shared__ float red2[256];
  __shared__ float stS[128];
  __shared__ float stB[128];

  const int t    = threadIdx.x;
  const int blk  = blockIdx.x;
  const int lane = t & 63;
  const int w    = t >> 6;            // wave 0..7
  const int b    = blk >> 7;
  const int n0   = (blk & 127) * 32;
  const int o    = t & 127;
  const int rgrp = t >> 7;            // rows rgrp*8 .. +7

  // ---------------- feat: block's 32 rows -> bufA[row][0..159] ----------------
  {
    float v0x=p.vertex[0], v0y=p.vertex[1], v0z=p.vertex[2];
    float r  = __fsqrt_rn(fadd(fadd(fmul(v0x,v0x),fmul(v0y,v0y)),fmul(v0z,v0z)));
    float rr = fmul(r,r);
    int j0 = p.nidx[0];
    float ax=p.vertex[3*j0], ay=p.vertex[3*j0+1], az=p.vertex[3*j0+2];
    float dx=fsub(v0x,ax), dy=fsub(v0y,ay), dz=fsub(v0z,az);
    float t2 = fadd(fadd(fmul(dx,dx),fmul(dy,dy)),fmul(dz,dz));

    int firsts[4]; int hass[4];
    #pragma unroll
    for (int rr_i=0; rr_i<4; rr_i++){
      const int row = w*4 + rr_i;
      const int n = n0 + row;
      const float* ob = p.orig + (b*19)*NPTS + n;
      float x=ob[0], y=ob[NPTS], z=ob[2*NPTS];
      float nrm = __fsqrt_rn(fadd(fadd(fmul(x,x),fmul(y,y)),fmul(z,z)));
      float s = __fdiv_rn(r,nrm);
      float px=fmul(x,s), py=fmul(y,s), pz=fmul(z,s);
      int first=0, has=0;
      for (int c0=0; c0<N0V; c0+=64){
        int m=c0+lane; bool hit=false;
        if (m<N0V){
          float vx=p.vertex[3*m], vy=p.vertex[3*m+1], vz=p.vertex[3*m+2];
          float v2=fadd(fadd(fmul(vx,vx),fmul(vy,vy)),fmul(vz,vz));
          float dt=fadd(fadd(fmul(px,vx),fmul(py,vy)),fmul(pz,vz));
          float d2=fsub(fadd(rr,v2),fmul(2.0f,dt));
          hit = (d2<=t2);
        }
        unsigned long long bal=__ballot(hit);
        if (bal){ first=c0+__builtin_ctzll(bal); has=1; break; }
      }
      firsts[rr_i]=first; hass[rr_i]=has;
    }
    const float* pb = p.proj + (long)b*128*N0V;
    #pragma unroll
    for (int rr_i=0; rr_i<4; rr_i++){
      const int row = w*4 + rr_i;
      const int n = n0 + row;
      #pragma unroll
      for (int k=0;k<3;k++){
        int idx = lane + k*64;
        if (idx < 160){
          float v;
          if (idx < 19)        v = p.orig[(b*19+idx)*NPTS + n];
          else if (idx < 147)  v = hass[rr_i] ? pb[(long)(idx-19)*N0V + firsts[rr_i]] : 0.0f;
          else                 v = 0.0f;
          bufA[row*160 + idx] = v;
        }
      }
    }
  }
  __syncthreads();

  float acc[8];

  // ---------------- layer 0 ----------------
  mm_compute<40>((const float4*)bufA, 40, p.wt0, p.b0, o, rgrp, acc);
  #pragma unroll
  for (int r=0;r<8;r++) bufB[(rgrp*8+r)*132 + o] = acc[r];
  layer_stats(acc, p.accg,        p.cnt,   p.g0, p.be0, redp, red2, stS, stB, t, blk);
  transform_buf(bufB, stS, stB, t);

  // ---------------- layer 1 ----------------
  mm_compute<32>((const float4*)bufB, 33, p.wt1, p.b1, o, rgrp, acc);
  #pragma unroll
  for (int r=0;r<8;r++) bufA[(rgrp*8+r)*132 + o] = acc[r];
  layer_stats(acc, p.accg + 4096, p.cnt+1, p.g1, p.be1, redp, red2, stS, stB, t, blk);
  transform_buf(bufA, stS, stB, t);

  // ---------------- layer 2 ----------------
  mm_compute<32>((const float4*)bufA, 33, p.wt2, p.b2, o, rgrp, acc);
  layer_stats(acc, p.accg + 8192, p.cnt+2, p.g2, p.be2, redp, red2, stS, stB, t, blk);

  // affine+relu in regs -> LDS -> coalesced transposed store
  {
    float ss = stS[o], sb = stB[o];
    #pragma unroll
    for (int r=0;r<8;r++)
      bufB[(rgrp*8+r)*132 + o] = fmaxf(fmaf(acc[r], ss, sb), 0.0f);
  }
  __syncthreads();
  {
    float* ob = p.out + (long)b*128*NPTS + n0;
    int oo = t >> 2, j0c = (t & 3) * 4;          // 128 outputs x 32 rows via 2 float4/thread
    #pragma unroll
    for (int half=0; half<2; half++){
      int j = j0c + half*16;
      float4 v;
      v.x = bufB[(j  )*132 + oo];
      v.y = bufB[(j+1)*132 + oo];
      v.z = bufB[(j+2)*132 + oo];
      v.w = bufB[(j+3)*132 + oo];
      *(float4*)(ob + (long)oo*NPTS + j) = v;
    }
  }
}

extern "C" void kernel_launch(void* const* d_in, const int* in_sizes, int n_in,
                              void* d_out, int out_size, void* d_ws, size_t ws_size,
                              hipStream_t stream)
{
  const float* orig   = (const float*)d_in[0];
  const float* proj   = (const float*)d_in[1];
  const float* vertex = (const float*)d_in[2];
  const int*   nidx   = (const int*)d_in[3];
  const float* W0 = (const float*)d_in[4];
  const float* b0 = (const float*)d_in[5];
  const float* g0 = (const float*)d_in[6];
  const float* be0= (const float*)d_in[7];
  const float* W1 = (const float*)d_in[8];
  const float* b1 = (const float*)d_in[9];
  const float* g1 = (const float*)d_in[10];
  const float* be1= (const float*)d_in[11];
  const float* W2 = (const float*)d_in[12];
  const float* b2 = (const float*)d_in[13];
  const float* g2 = (const float*)d_in[14];
  const float* be2= (const float*)d_in[15];
  float* out = (float*)d_out;

  float* ws   = (float*)d_ws;
  float* accg = ws;                         // 3*16*256 = 12288 floats
  int*   cnt  = (int*)(ws + 12288);         // 4 ints
  float* wt0  = ws + 12304;                 // 40*128*4 = 20480 floats (16B aligned)
  float* wt1  = wt0 + 20480;                // 16384
  float* wt2  = wt1 + 16384;                // 16384

  k_init<<<64, 256, 0, stream>>>(W0, W1, W2, wt0, wt1, wt2, accg, cnt);

  Params p{orig, proj, vertex, nidx, wt0, wt1, wt2,
           b0, g0, be0, b1, g1, be1, b2, g2, be2,
           accg, cnt, out};
  void* args[] = {(void*)&p};
  hipLaunchCooperativeKernel((const void*)k_fused, dim3(NBLK), dim3(512), args, 0, stream);
}

// Round 5
// 79.423 us; speedup vs baseline: 2.0909x; 1.2055x over previous
//
#include <hip/hip_runtime.h>

#define NPTS 4096
#define N0V  10242
#define EPSV 1e-5f
#define NBLK 256
#define SLOTS 16

__device__ __forceinline__ float fmul(float a,float b){return __fmul_rn(a,b);}
__device__ __forceinline__ float fadd(float a,float b){return __fadd_rn(a,b);}
__device__ __forceinline__ float fsub(float a,float b){return __fsub_rn(a,b);}

// ---------------- prep: pack W^T, pack vertex{x,y,z,v2}, zero acc slots/counters ----------------
__global__ __launch_bounds__(256) void k_init(
    const float* __restrict__ W0, const float* __restrict__ W1, const float* __restrict__ W2,
    const float* __restrict__ vertex,
    float* __restrict__ wt0, float* __restrict__ wt1, float* __restrict__ wt2,
    float* __restrict__ vpk, float* __restrict__ accg, int* __restrict__ cnt)
{
  int t = blockIdx.x * 256 + threadIdx.x;
  if (t < 5120) {                                  // wt0: [40][128] float4 (K=147 zero-padded)
    int c4 = t >> 7, o = t & 127;
    float4 v; float* vv = (float*)&v;
    #pragma unroll
    for (int j = 0; j < 4; j++) { int c = c4*4 + j; vv[j] = (c < 147) ? W0[o*147 + c] : 0.0f; }
    ((float4*)wt0)[t] = v;
  } else if (t < 9216) {                           // wt1: [32][128] float4
    int u = t - 5120; int c4 = u >> 7, o = u & 127;
    float4 v; float* vv = (float*)&v;
    #pragma unroll
    for (int j = 0; j < 4; j++) vv[j] = W1[o*128 + c4*4 + j];
    ((float4*)wt1)[u] = v;
  } else if (t < 13312) {                          // wt2
    int u = t - 9216; int c4 = u >> 7, o = u & 127;
    float4 v; float* vv = (float*)&v;
    #pragma unroll
    for (int j = 0; j < 4; j++) vv[j] = W2[o*128 + c4*4 + j];
    ((float4*)wt2)[u] = v;
  } else if (t < 16384) {                          // zero 3*16*256 = 12288 floats + counters
    int u = t - 13312;
    ((float4*)accg)[u] = make_float4(0.f,0.f,0.f,0.f);
    if (u < 4) cnt[u] = 0;
  } else if (t < 16384 + N0V) {                    // vpk[m] = {x,y,z,|v|^2}
    int m = t - 16384;
    float x = vertex[3*m], y = vertex[3*m+1], z = vertex[3*m+2];
    float v2 = fadd(fadd(fmul(x,x),fmul(y,y)),fmul(z,z));
    ((float4*)vpk)[m] = make_float4(x,y,z,v2);
  }
}

struct Params {
  const float* orig; const float* proj; const float* vertex; const int* nidx;
  const float* wt0; const float* wt1; const float* wt2; const float* vpk;
  const float* b0; const float* g0; const float* be0;
  const float* b1; const float* g1; const float* be1;
  const float* b2; const float* g2; const float* be2;
  float* accg; int* cnt; float* out;
};

// dot-product core: thread = (o, rgrp 0..7); 4 rows each; x from LDS (broadcast), W from L1/L2
template<int K4>
__device__ __forceinline__ void mm_compute(const float4* xs4, int xstr4,
                                           const float* __restrict__ wt,
                                           const float* __restrict__ bias,
                                           int o, int rgrp, float* acc)
{
  #pragma unroll
  for (int r=0;r<4;r++) acc[r]=0.0f;
  const float4* wp = ((const float4*)wt) + o;
  #pragma unroll
  for (int c4=0;c4<K4;c4++){
    float4 wv = wp[c4*128];
    #pragma unroll
    for (int r=0;r<4;r++){
      float4 xv = xs4[(rgrp*4+r)*xstr4 + c4];
      acc[r]=fmaf(xv.x,wv.x,acc[r]);
      acc[r]=fmaf(xv.y,wv.y,acc[r]);
      acc[r]=fmaf(xv.z,wv.z,acc[r]);
      acc[r]=fmaf(xv.w,wv.w,acc[r]);
    }
  }
  float bo = bias[o];
  #pragma unroll
  for (int r=0;r<4;r++) acc[r] += bo;
}

// partials -> global atomic slots -> counter barrier -> redundant small stats -> stS/stB in LDS
__device__ __forceinline__ void layer_stats(const float* acc4,
    float* __restrict__ accL, int* __restrict__ cntp,
    const float* __restrict__ g, const float* __restrict__ be,
    float* redp, float* red2, float* stS, float* stB, int t, int blk)
{
  float s1=0.0f, s2=0.0f;
  #pragma unroll
  for (int r=0;r<4;r++){ s1 += acc4[r]; s2 = fmaf(acc4[r],acc4[r],s2); }
  int o = t & 127, rgrp = t >> 7;
  redp[rgrp*128 + o]        = s1;
  redp[1024 + rgrp*128 + o] = s2;
  __syncthreads();
  if (t < 256){
    int q = t >> 7, ch = t & 127;
    const float* rp = redp + q*1024 + ch;
    float v = ((rp[0]+rp[128])+(rp[256]+rp[384])) + ((rp[512]+rp[640])+(rp[768]+rp[896]));
    atomicAdd(&accL[(blk & (SLOTS-1))*256 + t], v);   // device-scope, coherent point
  }
  __syncthreads();   // s_waitcnt vmcnt(0): this block's atomics globally performed
  if (t == 0){
    __hip_atomic_fetch_add(cntp, 1, __ATOMIC_RELEASE, __HIP_MEMORY_SCOPE_AGENT);
    while (__hip_atomic_load(cntp, __ATOMIC_ACQUIRE, __HIP_MEMORY_SCOPE_AGENT) < NBLK)
      __builtin_amdgcn_s_sleep(2);
  }
  __syncthreads();
  if (t < 256){
    float v = 0.0f;
    #pragma unroll
    for (int s=0;s<SLOTS;s++)
      v += __hip_atomic_load(&accL[s*256 + t], __ATOMIC_RELAXED, __HIP_MEMORY_SCOPE_AGENT);
    red2[t] = v;
  }
  __syncthreads();
  if (t < 128){
    float S = red2[t], Q = red2[128 + t];
    float mean = S * (1.0f/8192.0f);
    float var  = Q * (1.0f/8192.0f) - mean*mean;
    float inv  = 1.0f / __fsqrt_rn(var + EPSV);
    float sc = g[t]*inv;
    stS[t] = sc;
    stB[t] = be[t] - mean*sc;
  }
  __syncthreads();
}

// in-place affine+relu on [32][132] tile (f4 stride 33, cols 0..127); 1024 threads, 1 f4 each
__device__ __forceinline__ void transform_buf(float* buf, const float* stS, const float* stB, int t)
{
  float4* b4 = (float4*)buf;
  int r = t >> 5, c4 = t & 31;
  float4 v = b4[r*33 + c4];
  int c = c4*4;
  v.x = fmaxf(fmaf(v.x, stS[c  ], stB[c  ]), 0.0f);
  v.y = fmaxf(fmaf(v.y, stS[c+1], stB[c+1]), 0.0f);
  v.z = fmaxf(fmaf(v.z, stS[c+2], stB[c+2]), 0.0f);
  v.w = fmaxf(fmaf(v.w, stS[c+3], stB[c+3]), 0.0f);
  b4[r*33 + c4] = v;
  __syncthreads();
}

__global__ __launch_bounds__(1024) void k_fused(Params p)
{
  __shared__ __align__(16) float bufA[32*160];   // x0 [32][160]; later y1/x2 [32][132]
  __shared__ __align__(16) float bufB[32*132];   // y0/x1; later y2
  __shared__ float redp[2048];
  __shared__ float red2[256];
  __shared__ float stS[128];
  __shared__ float stB[128];

  const int t    = threadIdx.x;
  const int blk  = blockIdx.x;
  const int lane = t & 63;
  const int w    = t >> 6;            // wave 0..15
  const int b    = blk >> 7;
  const int n0   = (blk & 127) * 32;
  const int o    = t & 127;
  const int rgrp = t >> 7;            // 0..7 -> rows rgrp*4 .. +3

  // ---------------- feat: block's 32 rows -> bufA[row][0..159]; 2 rows per wave ----------------
  {
    float v0x=p.vertex[0], v0y=p.vertex[1], v0z=p.vertex[2];
    float r  = __fsqrt_rn(fadd(fadd(fmul(v0x,v0x),fmul(v0y,v0y)),fmul(v0z,v0z)));
    float rr = fmul(r,r);
    int j0 = p.nidx[0];
    float ax=p.vertex[3*j0], ay=p.vertex[3*j0+1], az=p.vertex[3*j0+2];
    float dx=fsub(v0x,ax), dy=fsub(v0y,ay), dz=fsub(v0z,az);
    float t2 = fadd(fadd(fmul(dx,dx),fmul(dy,dy)),fmul(dz,dz));
    const float4* vp4 = (const float4*)p.vpk;

    int firsts[2]; int hass[2];
    #pragma unroll
    for (int rr_i=0; rr_i<2; rr_i++){
      const int row = w*2 + rr_i;
      const int n = n0 + row;
      const float* ob = p.orig + (b*19)*NPTS + n;
      float x=ob[0], y=ob[NPTS], z=ob[2*NPTS];
      float nrm = __fsqrt_rn(fadd(fadd(fmul(x,x),fmul(y,y)),fmul(z,z)));
      float s = __fdiv_rn(r,nrm);
      float px=fmul(x,s), py=fmul(y,s), pz=fmul(z,s);
      int first=0, has=0;
      for (int c0=0; c0<N0V; c0+=256){           // 4 chunks in flight per iteration
        int m0=c0+lane, m1=m0+64, m2=m0+128, m3=m0+192;
        float4 va = vp4[min(m0, N0V-1)];
        float4 vb = vp4[min(m1, N0V-1)];
        float4 vc = vp4[min(m2, N0V-1)];
        float4 vd = vp4[min(m3, N0V-1)];
        float dta = fadd(fadd(fmul(px,va.x),fmul(py,va.y)),fmul(pz,va.z));
        float dtb = fadd(fadd(fmul(px,vb.x),fmul(py,vb.y)),fmul(pz,vb.z));
        float dtc = fadd(fadd(fmul(px,vc.x),fmul(py,vc.y)),fmul(pz,vc.z));
        float dtd = fadd(fadd(fmul(px,vd.x),fmul(py,vd.y)),fmul(pz,vd.z));
        bool h0 = (m0<N0V) && (fsub(fadd(rr,va.w),fmul(2.0f,dta)) <= t2);
        bool h1 = (m1<N0V) && (fsub(fadd(rr,vb.w),fmul(2.0f,dtb)) <= t2);
        bool h2 = (m2<N0V) && (fsub(fadd(rr,vc.w),fmul(2.0f,dtc)) <= t2);
        bool h3 = (m3<N0V) && (fsub(fadd(rr,vd.w),fmul(2.0f,dtd)) <= t2);
        unsigned long long bal;
        if ((bal=__ballot(h0))){ first=c0     +__builtin_ctzll(bal); has=1; break; }
        if ((bal=__ballot(h1))){ first=c0+ 64+__builtin_ctzll(bal); has=1; break; }
        if ((bal=__ballot(h2))){ first=c0+128+__builtin_ctzll(bal); has=1; break; }
        if ((bal=__ballot(h3))){ first=c0+192+__builtin_ctzll(bal); has=1; break; }
      }
      firsts[rr_i]=first; hass[rr_i]=has;
    }
    const float* pb = p.proj + (long)b*128*N0V;
    #pragma unroll
    for (int rr_i=0; rr_i<2; rr_i++){
      const int row = w*2 + rr_i;
      const int n = n0 + row;
      #pragma unroll
      for (int k=0;k<3;k++){
        int idx = lane + k*64;
        if (idx < 160){
          float v;
          if (idx < 19)        v = p.orig[(b*19+idx)*NPTS + n];
          else if (idx < 147)  v = hass[rr_i] ? pb[(long)(idx-19)*N0V + firsts[rr_i]] : 0.0f;
          else                 v = 0.0f;
          bufA[row*160 + idx] = v;
        }
      }
    }
  }
  __syncthreads();

  float acc[4];

  // ---------------- layer 0 ----------------
  mm_compute<40>((const float4*)bufA, 40, p.wt0, p.b0, o, rgrp, acc);
  #pragma unroll
  for (int r=0;r<4;r++) bufB[(rgrp*4+r)*132 + o] = acc[r];
  layer_stats(acc, p.accg,        p.cnt,   p.g0, p.be0, redp, red2, stS, stB, t, blk);
  transform_buf(bufB, stS, stB, t);

  // ---------------- layer 1 ----------------
  mm_compute<32>((const float4*)bufB, 33, p.wt1, p.b1, o, rgrp, acc);
  #pragma unroll
  for (int r=0;r<4;r++) bufA[(rgrp*4+r)*132 + o] = acc[r];
  layer_stats(acc, p.accg + 4096, p.cnt+1, p.g1, p.be1, redp, red2, stS, stB, t, blk);
  transform_buf(bufA, stS, stB, t);

  // ---------------- layer 2 ----------------
  mm_compute<32>((const float4*)bufA, 33, p.wt2, p.b2, o, rgrp, acc);
  layer_stats(acc, p.accg + 8192, p.cnt+2, p.g2, p.be2, redp, red2, stS, stB, t, blk);

  // affine+relu in regs -> LDS -> coalesced transposed store
  {
    float ss = stS[o], sb = stB[o];
    #pragma unroll
    for (int r=0;r<4;r++)
      bufB[(rgrp*4+r)*132 + o] = fmaxf(fmaf(acc[r], ss, sb), 0.0f);
  }
  __syncthreads();
  {
    float* ob = p.out + (long)b*128*NPTS + n0;
    int oo = t >> 3, j = (t & 7) * 4;            // 128 outputs x 32 rows, 1 float4/thread
    float4 v;
    v.x = bufB[(j  )*132 + oo];
    v.y = bufB[(j+1)*132 + oo];
    v.z = bufB[(j+2)*132 + oo];
    v.w = bufB[(j+3)*132 + oo];
    *(float4*)(ob + (long)oo*NPTS + j) = v;
  }
}

extern "C" void kernel_launch(void* const* d_in, const int* in_sizes, int n_in,
                              void* d_out, int out_size, void* d_ws, size_t ws_size,
                              hipStream_t stream)
{
  const float* orig   = (const float*)d_in[0];
  const float* proj   = (const float*)d_in[1];
  const float* vertex = (const float*)d_in[2];
  const int*   nidx   = (const int*)d_in[3];
  const float* W0 = (const float*)d_in[4];
  const float* b0 = (const float*)d_in[5];
  const float* g0 = (const float*)d_in[6];
  const float* be0= (const float*)d_in[7];
  const float* W1 = (const float*)d_in[8];
  const float* b1 = (const float*)d_in[9];
  const float* g1 = (const float*)d_in[10];
  const float* be1= (const float*)d_in[11];
  const float* W2 = (const float*)d_in[12];
  const float* b2 = (const float*)d_in[13];
  const float* g2 = (const float*)d_in[14];
  const float* be2= (const float*)d_in[15];
  float* out = (float*)d_out;

  float* ws   = (float*)d_ws;
  float* accg = ws;                         // 3*16*256 = 12288 floats
  int*   cnt  = (int*)(ws + 12288);         // 4 ints (pad to 16)
  float* wt0  = ws + 12304;                 // 5120 float4 = 20480 floats
  float* wt1  = wt0 + 20480;                // 16384
  float* wt2  = wt1 + 16384;                // 16384
  float* vpk  = wt2 + 16384;                // 10242 float4 = 40968 floats

  k_init<<<105, 256, 0, stream>>>(W0, W1, W2, vertex, wt0, wt1, wt2, vpk, accg, cnt);

  Params p{orig, proj, vertex, nidx, wt0, wt1, wt2, vpk,
           b0, g0, be0, b1, g1, be1, b2, g2, be2,
           accg, cnt, out};
  void* args[] = {(void*)&p};
  hipLaunchCooperativeKernel((const void*)k_fused, dim3(NBLK), dim3(1024), args, 0, stream);
}

// Round 6
// 77.865 us; speedup vs baseline: 2.1328x; 1.0200x over previous
//
#include <hip/hip_runtime.h>

#define NPTS 4096
#define N0V  10242
#define EPSV 1e-5f
#define NBLK 256
#define SLOTS 16

__device__ __forceinline__ float fmul(float a,float b){return __fmul_rn(a,b);}
__device__ __forceinline__ float fadd(float a,float b){return __fadd_rn(a,b);}
__device__ __forceinline__ float fsub(float a,float b){return __fsub_rn(a,b);}

// ---------------- prep: pack W^T, pack vertex{x,y,z,v2}, zero acc slots/counters ----------------
__global__ __launch_bounds__(256) void k_init(
    const float* __restrict__ W0, const float* __restrict__ W1, const float* __restrict__ W2,
    const float* __restrict__ vertex,
    float* __restrict__ wt0, float* __restrict__ wt1, float* __restrict__ wt2,
    float* __restrict__ vpk, float* __restrict__ accg, int* __restrict__ cnt)
{
  int t = blockIdx.x * 256 + threadIdx.x;
  if (t < 5120) {                                  // wt0: [40][128] float4 (K=147 zero-padded)
    int c4 = t >> 7, o = t & 127;
    float4 v; float* vv = (float*)&v;
    #pragma unroll
    for (int j = 0; j < 4; j++) { int c = c4*4 + j; vv[j] = (c < 147) ? W0[o*147 + c] : 0.0f; }
    ((float4*)wt0)[t] = v;
  } else if (t < 9216) {                           // wt1: [32][128] float4
    int u = t - 5120; int c4 = u >> 7, o = u & 127;
    float4 v; float* vv = (float*)&v;
    #pragma unroll
    for (int j = 0; j < 4; j++) vv[j] = W1[o*128 + c4*4 + j];
    ((float4*)wt1)[u] = v;
  } else if (t < 13312) {                          // wt2
    int u = t - 9216; int c4 = u >> 7, o = u & 127;
    float4 v; float* vv = (float*)&v;
    #pragma unroll
    for (int j = 0; j < 4; j++) vv[j] = W2[o*128 + c4*4 + j];
    ((float4*)wt2)[u] = v;
  } else if (t < 16384) {                          // zero 3*16*256 = 12288 floats + counters
    int u = t - 13312;
    ((float4*)accg)[u] = make_float4(0.f,0.f,0.f,0.f);
    if (u < 4) cnt[u] = 0;
  } else if (t < 16384 + N0V) {                    // vpk[m] = {x,y,z,|v|^2}
    int m = t - 16384;
    float x = vertex[3*m], y = vertex[3*m+1], z = vertex[3*m+2];
    float v2 = fadd(fadd(fmul(x,x),fmul(y,y)),fmul(z,z));
    ((float4*)vpk)[m] = make_float4(x,y,z,v2);
  }
}

struct Params {
  const float* orig; const float* proj; const float* vertex; const int* nidx;
  const float* wt0; const float* wt1; const float* wt2; const float* vpk;
  const float* b0; const float* g0; const float* be0;
  const float* b1; const float* g1; const float* be1;
  const float* b2; const float* g2; const float* be2;
  float* accg; int* cnt; float* out;
};

// dot-product core with explicit software pipeline:
//   - 6-deep register rotation of weight float4s (keeps 6 global loads in flight)
//   - 1-deep prefetch of the 4 LDS x-fragments
// All buffer indices are compile-time constants after full unroll (no scratch).
template<int K4>
__device__ __forceinline__ void mm_compute(const float4* xs4, int xstr4,
                                           const float* __restrict__ wt,
                                           const float* __restrict__ bias,
                                           int o, int rgrp, float* acc)
{
  constexpr int PF = 6;
  const float4* wp = ((const float4*)wt) + o;
  const float4* xb = xs4 + rgrp*4*xstr4;

  float4 wbuf[PF];
  #pragma unroll
  for (int i=0;i<PF;i++) wbuf[i] = wp[i*128];
  float4 xbuf[4];
  #pragma unroll
  for (int r=0;r<4;r++) xbuf[r] = xb[r*xstr4];

  #pragma unroll
  for (int r=0;r<4;r++) acc[r]=0.0f;

  #pragma unroll
  for (int c4=0;c4<K4;c4++){
    float4 wv = wbuf[c4%PF];
    if (c4+PF < K4) wbuf[c4%PF] = wp[(c4+PF)*128];   // issue ahead; vmcnt-counted wait
    float4 x0=xbuf[0], x1=xbuf[1], x2=xbuf[2], x3=xbuf[3];
    if (c4+1 < K4) {
      #pragma unroll
      for (int r=0;r<4;r++) xbuf[r] = xb[r*xstr4 + (c4+1)];
    }
    acc[0]=fmaf(x0.x,wv.x,acc[0]); acc[0]=fmaf(x0.y,wv.y,acc[0]);
    acc[0]=fmaf(x0.z,wv.z,acc[0]); acc[0]=fmaf(x0.w,wv.w,acc[0]);
    acc[1]=fmaf(x1.x,wv.x,acc[1]); acc[1]=fmaf(x1.y,wv.y,acc[1]);
    acc[1]=fmaf(x1.z,wv.z,acc[1]); acc[1]=fmaf(x1.w,wv.w,acc[1]);
    acc[2]=fmaf(x2.x,wv.x,acc[2]); acc[2]=fmaf(x2.y,wv.y,acc[2]);
    acc[2]=fmaf(x2.z,wv.z,acc[2]); acc[2]=fmaf(x2.w,wv.w,acc[2]);
    acc[3]=fmaf(x3.x,wv.x,acc[3]); acc[3]=fmaf(x3.y,wv.y,acc[3]);
    acc[3]=fmaf(x3.z,wv.z,acc[3]); acc[3]=fmaf(x3.w,wv.w,acc[3]);
  }
  float bo = bias[o];
  #pragma unroll
  for (int r=0;r<4;r++) acc[r] += bo;
}

// partials -> global atomic slots -> counter barrier -> redundant small stats -> stS/stB in LDS
__device__ __forceinline__ void layer_stats(const float* acc4,
    float* __restrict__ accL, int* __restrict__ cntp,
    const float* __restrict__ g, const float* __restrict__ be,
    float* redp, float* red2, float* stS, float* stB, int t, int blk)
{
  float s1=0.0f, s2=0.0f;
  #pragma unroll
  for (int r=0;r<4;r++){ s1 += acc4[r]; s2 = fmaf(acc4[r],acc4[r],s2); }
  int o = t & 127, rgrp = t >> 7;
  redp[rgrp*128 + o]        = s1;
  redp[1024 + rgrp*128 + o] = s2;
  __syncthreads();
  if (t < 256){
    int q = t >> 7, ch = t & 127;
    const float* rp = redp + q*1024 + ch;
    float v = ((rp[0]+rp[128])+(rp[256]+rp[384])) + ((rp[512]+rp[640])+(rp[768]+rp[896]));
    atomicAdd(&accL[(blk & (SLOTS-1))*256 + t], v);   // device-scope, coherent point
  }
  __syncthreads();   // s_waitcnt vmcnt(0): this block's atomics globally performed
  if (t == 0){
    __hip_atomic_fetch_add(cntp, 1, __ATOMIC_RELEASE, __HIP_MEMORY_SCOPE_AGENT);
    while (__hip_atomic_load(cntp, __ATOMIC_ACQUIRE, __HIP_MEMORY_SCOPE_AGENT) < NBLK)
      __builtin_amdgcn_s_sleep(2);
  }
  __syncthreads();
  if (t < 256){
    float v = 0.0f;
    #pragma unroll
    for (int s=0;s<SLOTS;s++)
      v += __hip_atomic_load(&accL[s*256 + t], __ATOMIC_RELAXED, __HIP_MEMORY_SCOPE_AGENT);
    red2[t] = v;
  }
  __syncthreads();
  if (t < 128){
    float S = red2[t], Q = red2[128 + t];
    float mean = S * (1.0f/8192.0f);
    float var  = Q * (1.0f/8192.0f) - mean*mean;
    float inv  = 1.0f / __fsqrt_rn(var + EPSV);
    float sc = g[t]*inv;
    stS[t] = sc;
    stB[t] = be[t] - mean*sc;
  }
  __syncthreads();
}

// in-place affine+relu on [32][132] tile (f4 stride 33, cols 0..127); 1024 threads, 1 f4 each
__device__ __forceinline__ void transform_buf(float* buf, const float* stS, const float* stB, int t)
{
  float4* b4 = (float4*)buf;
  int r = t >> 5, c4 = t & 31;
  float4 v = b4[r*33 + c4];
  int c = c4*4;
  v.x = fmaxf(fmaf(v.x, stS[c  ], stB[c  ]), 0.0f);
  v.y = fmaxf(fmaf(v.y, stS[c+1], stB[c+1]), 0.0f);
  v.z = fmaxf(fmaf(v.z, stS[c+2], stB[c+2]), 0.0f);
  v.w = fmaxf(fmaf(v.w, stS[c+3], stB[c+3]), 0.0f);
  b4[r*33 + c4] = v;
  __syncthreads();
}

__global__ __launch_bounds__(1024) void k_fused(Params p)
{
  __shared__ __align__(16) float bufA[32*160];   // x0 [32][160]; later y1/x2 [32][132]
  __shared__ __align__(16) float bufB[32*132];   // y0/x1; later y2
  __shared__ float redp[2048];
  __shared__ float red2[256];
  __shared__ float stS[128];
  __shared__ float stB[128];

  const int t    = threadIdx.x;
  const int blk  = blockIdx.x;
  const int lane = t & 63;
  const int w    = t >> 6;            // wave 0..15
  const int b    = blk >> 7;
  const int n0   = (blk & 127) * 32;
  const int o    = t & 127;
  const int rgrp = t >> 7;            // 0..7 -> rows rgrp*4 .. +3

  // ---------------- feat: block's 32 rows -> bufA[row][0..159]; 2 rows per wave ----------------
  {
    float v0x=p.vertex[0], v0y=p.vertex[1], v0z=p.vertex[2];
    float r  = __fsqrt_rn(fadd(fadd(fmul(v0x,v0x),fmul(v0y,v0y)),fmul(v0z,v0z)));
    float rr = fmul(r,r);
    int j0 = p.nidx[0];
    float ax=p.vertex[3*j0], ay=p.vertex[3*j0+1], az=p.vertex[3*j0+2];
    float dx=fsub(v0x,ax), dy=fsub(v0y,ay), dz=fsub(v0z,az);
    float t2 = fadd(fadd(fmul(dx,dx),fmul(dy,dy)),fmul(dz,dz));
    const float4* vp4 = (const float4*)p.vpk;

    int firsts[2]; int hass[2];
    #pragma unroll
    for (int rr_i=0; rr_i<2; rr_i++){
      const int row = w*2 + rr_i;
      const int n = n0 + row;
      const float* ob = p.orig + (b*19)*NPTS + n;
      float x=ob[0], y=ob[NPTS], z=ob[2*NPTS];
      float nrm = __fsqrt_rn(fadd(fadd(fmul(x,x),fmul(y,y)),fmul(z,z)));
      float s = __fdiv_rn(r,nrm);
      float px=fmul(x,s), py=fmul(y,s), pz=fmul(z,s);
      int first=0, has=0;
      for (int c0=0; c0<N0V; c0+=256){           // 4 chunks in flight per iteration
        int m0=c0+lane, m1=m0+64, m2=m0+128, m3=m0+192;
        float4 va = vp4[min(m0, N0V-1)];
        float4 vb = vp4[min(m1, N0V-1)];
        float4 vc = vp4[min(m2, N0V-1)];
        float4 vd = vp4[min(m3, N0V-1)];
        float dta = fadd(fadd(fmul(px,va.x),fmul(py,va.y)),fmul(pz,va.z));
        float dtb = fadd(fadd(fmul(px,vb.x),fmul(py,vb.y)),fmul(pz,vb.z));
        float dtc = fadd(fadd(fmul(px,vc.x),fmul(py,vc.y)),fmul(pz,vc.z));
        float dtd = fadd(fadd(fmul(px,vd.x),fmul(py,vd.y)),fmul(pz,vd.z));
        bool h0 = (m0<N0V) && (fsub(fadd(rr,va.w),fmul(2.0f,dta)) <= t2);
        bool h1 = (m1<N0V) && (fsub(fadd(rr,vb.w),fmul(2.0f,dtb)) <= t2);
        bool h2 = (m2<N0V) && (fsub(fadd(rr,vc.w),fmul(2.0f,dtc)) <= t2);
        bool h3 = (m3<N0V) && (fsub(fadd(rr,vd.w),fmul(2.0f,dtd)) <= t2);
        unsigned long long bal;
        if ((bal=__ballot(h0))){ first=c0     +__builtin_ctzll(bal); has=1; break; }
        if ((bal=__ballot(h1))){ first=c0+ 64+__builtin_ctzll(bal); has=1; break; }
        if ((bal=__ballot(h2))){ first=c0+128+__builtin_ctzll(bal); has=1; break; }
        if ((bal=__ballot(h3))){ first=c0+192+__builtin_ctzll(bal); has=1; break; }
      }
      firsts[rr_i]=first; hass[rr_i]=has;
    }
    const float* pb = p.proj + (long)b*128*N0V;
    #pragma unroll
    for (int rr_i=0; rr_i<2; rr_i++){
      const int row = w*2 + rr_i;
      const int n = n0 + row;
      #pragma unroll
      for (int k=0;k<3;k++){
        int idx = lane + k*64;
        if (idx < 160){
          float v;
          if (idx < 19)        v = p.orig[(b*19+idx)*NPTS + n];
          else if (idx < 147)  v = hass[rr_i] ? pb[(long)(idx-19)*N0V + firsts[rr_i]] : 0.0f;
          else                 v = 0.0f;
          bufA[row*160 + idx] = v;
        }
      }
    }
  }
  __syncthreads();

  float acc[4];

  // ---------------- layer 0 ----------------
  mm_compute<40>((const float4*)bufA, 40, p.wt0, p.b0, o, rgrp, acc);
  #pragma unroll
  for (int r=0;r<4;r++) bufB[(rgrp*4+r)*132 + o] = acc[r];
  layer_stats(acc, p.accg,        p.cnt,   p.g0, p.be0, redp, red2, stS, stB, t, blk);
  transform_buf(bufB, stS, stB, t);

  // ---------------- layer 1 ----------------
  mm_compute<32>((const float4*)bufB, 33, p.wt1, p.b1, o, rgrp, acc);
  #pragma unroll
  for (int r=0;r<4;r++) bufA[(rgrp*4+r)*132 + o] = acc[r];
  layer_stats(acc, p.accg + 4096, p.cnt+1, p.g1, p.be1, redp, red2, stS, stB, t, blk);
  transform_buf(bufA, stS, stB, t);

  // ---------------- layer 2 ----------------
  mm_compute<32>((const float4*)bufA, 33, p.wt2, p.b2, o, rgrp, acc);
  layer_stats(acc, p.accg + 8192, p.cnt+2, p.g2, p.be2, redp, red2, stS, stB, t, blk);

  // affine+relu in regs -> LDS -> coalesced transposed store
  {
    float ss = stS[o], sb = stB[o];
    #pragma unroll
    for (int r=0;r<4;r++)
      bufB[(rgrp*4+r)*132 + o] = fmaxf(fmaf(acc[r], ss, sb), 0.0f);
  }
  __syncthreads();
  {
    float* ob = p.out + (long)b*128*NPTS + n0;
    int oo = t >> 3, j = (t & 7) * 4;            // 128 outputs x 32 rows, 1 float4/thread
    float4 v;
    v.x = bufB[(j  )*132 + oo];
    v.y = bufB[(j+1)*132 + oo];
    v.z = bufB[(j+2)*132 + oo];
    v.w = bufB[(j+3)*132 + oo];
    *(float4*)(ob + (long)oo*NPTS + j) = v;
  }
}

extern "C" void kernel_launch(void* const* d_in, const int* in_sizes, int n_in,
                              void* d_out, int out_size, void* d_ws, size_t ws_size,
                              hipStream_t stream)
{
  const float* orig   = (const float*)d_in[0];
  const float* proj   = (const float*)d_in[1];
  const float* vertex = (const float*)d_in[2];
  const int*   nidx   = (const int*)d_in[3];
  const float* W0 = (const float*)d_in[4];
  const float* b0 = (const float*)d_in[5];
  const float* g0 = (const float*)d_in[6];
  const float* be0= (const float*)d_in[7];
  const float* W1 = (const float*)d_in[8];
  const float* b1 = (const float*)d_in[9];
  const float* g1 = (const float*)d_in[10];
  const float* be1= (const float*)d_in[11];
  const float* W2 = (const float*)d_in[12];
  const float* b2 = (const float*)d_in[13];
  const float* g2 = (const float*)d_in[14];
  const float* be2= (const float*)d_in[15];
  float* out = (float*)d_out;

  float* ws   = (float*)d_ws;
  float* accg = ws;                         // 3*16*256 = 12288 floats
  int*   cnt  = (int*)(ws + 12288);         // 4 ints (pad to 16)
  float* wt0  = ws + 12304;                 // 5120 float4 = 20480 floats
  float* wt1  = wt0 + 20480;                // 16384
  float* wt2  = wt1 + 16384;                // 16384
  float* vpk  = wt2 + 16384;                // 10242 float4 = 40968 floats

  k_init<<<105, 256, 0, stream>>>(W0, W1, W2, vertex, wt0, wt1, wt2, vpk, accg, cnt);

  Params p{orig, proj, vertex, nidx, wt0, wt1, wt2, vpk,
           b0, g0, be0, b1, g1, be1, b2, g2, be2,
           accg, cnt, out};
  void* args[] = {(void*)&p};
  hipLaunchCooperativeKernel((const void*)k_fused, dim3(NBLK), dim3(1024), args, 0, stream);
}